// Round 7
// baseline (160.842 us; speedup 1.0000x reference)
//
#include <hip/hip_runtime.h>
#include <hip/hip_bf16.h>

// B=8, H=W=1024, N=4096, R=8 -> d=17, patch=289, out (B,4096,578) fp32.
// p1[b,n,j] = image1[b, m1 + j%17 - 8, m0 + j//17 - 8]  (zero-pad OOB)
// p2[b,n,j] = image2[b, m3 + j%17 - 8, m2 + j//17 - 8]
// normalize each 289-vector: (p - mean) / (std_ddof1 + 1e-4)
//
// R7: replace the 15us LLC-prewarm with PROCESSING-ORDER LOCALITY.
// Counting-sort the 65536 patch-tasks by key = (batch, image, y>>4) into
// d_ws (4 tiny kernels), then extract processes tasks in sorted order:
// concurrent blocks read a ~32-row (128 KB) band per image that sweeps
// memory -> quasi-streaming HBM reads + L2 line reuse, no prewarm needed.
// Output stores stay per-patch contiguous (1.2 KB chunks, order-independent).

#define IMG_H 1024
#define IMG_W 1024
#define NMATCH 4096
#define DPATCH 17
#define NPATCH 289
#define RAD 8
#define HW (IMG_H * IMG_W)
#define NTASK 65536           // 8 batches * 4096 pairs * 2 images
#define NBUCKET 1024          // (b:3)(which:1)(ybucket:6)

// d_ws layout: int hist[1024] @ 0 ; int tasks[65536] @ 4096 bytes

__device__ __forceinline__ int task_key(const int* matches, int t) {
    const int pair  = t >> 1;
    const int which = t & 1;
    const int my = matches[pair * 4 + (which ? 3 : 1)];
    return (((pair >> 12) << 1 | which) << 6) | ((my >> 4) & 63);
}

__global__ __launch_bounds__(256) void zero_hist_kernel(int* __restrict__ hist) {
    const int i = threadIdx.x;
#pragma unroll
    for (int k = 0; k < NBUCKET / 256; ++k) hist[i + k * 256] = 0;
}

__global__ __launch_bounds__(256) void hist_kernel(
    const int* __restrict__ matches, int* __restrict__ hist) {
    const int t = blockIdx.x * blockDim.x + threadIdx.x;   // 0..65535
    atomicAdd(&hist[task_key(matches, t)], 1);
}

// single block of 64 lanes: exclusive prefix sum of hist[1024] in place
__global__ __launch_bounds__(64) void scan_kernel(int* __restrict__ hist) {
    const int lane = threadIdx.x;
    int local[16];
    int s = 0;
#pragma unroll
    for (int i = 0; i < 16; ++i) {
        local[i] = s;
        s += hist[lane * 16 + i];
    }
    // exclusive prefix of per-lane totals across 64 lanes
    int pre = s;
#pragma unroll
    for (int off = 1; off < 64; off <<= 1) {
        int t = __shfl_up(pre, off, 64);
        if (lane >= off) pre += t;
    }
    pre -= s;
#pragma unroll
    for (int i = 0; i < 16; ++i) {
        hist[lane * 16 + i] = pre + local[i];
    }
}

__global__ __launch_bounds__(256) void scatter_kernel(
    const int* __restrict__ matches, int* __restrict__ hist,
    int* __restrict__ tasks) {
    const int t = blockIdx.x * blockDim.x + threadIdx.x;
    const int pos = atomicAdd(&hist[task_key(matches, t)], 1);
    tasks[pos] = t;
}

__global__ __launch_bounds__(256) void extract_patch_kernel(
    const float* __restrict__ img1,
    const float* __restrict__ img2,
    const int* __restrict__ matches,
    const int* __restrict__ tasks,
    float* __restrict__ out)
{
    // 4 waves/block x 4 patches/wave x 289 floats = 18496 B
    __shared__ float smem[4 * 4 * NPATCH];

    const int tid   = blockIdx.x * blockDim.x + threadIdx.x;
    const int wave  = tid >> 6;            // 0 .. 16383
    const int lane  = tid & 63;
    const int wslot = threadIdx.x >> 6;    // 0..3

    // load-phase lane mapping: 3 groups x 17 lanes, lanes 51..63 idle
    const int g = lane / DPATCH;           // 0..2 active, 3 idle
    const int c = lane - g * DPATCH;       // 0..16 column within row segment
    const bool active = (g < 3);

    int task[4], mx[4], my[4];
    const float* ib[4];
    float* op[4];
#pragma unroll
    for (int t = 0; t < 4; ++t) {
        task[t] = tasks[4 * wave + t];     // sorted task ids
        const int pair  = task[t] >> 1;
        const int which = task[t] & 1;
        const int b = pair >> 12;
        mx[t] = matches[pair * 4 + (which ? 2 : 0)];
        my[t] = matches[pair * 4 + (which ? 3 : 1)];
        ib[t] = (which ? img2 : img1) + (size_t)b * HW;
        op[t] = out + (size_t)pair * 578 + which * NPATCH;
    }

    // ---- issue all 24 independent loads up front (branchless, select-to-0) ----
    float v[4][6];
#pragma unroll
    for (int t = 0; t < 4; ++t) {
        const int ix = mx[t] + c - RAD;
#pragma unroll
        for (int it = 0; it < 6; ++it) {
            const int r  = it * 3 + g;     // patch row; r==17 only at (it=5,g=2)
            const int iy = my[t] + r - RAD;
            const bool ok = active && (r < DPATCH) &&
                            ((unsigned)ix < IMG_W) && ((unsigned)iy < IMG_H);
            const int off = ok ? (iy * IMG_W + ix) : 0;
            const float val = ib[t][off];
            v[t][it] = ok ? val : 0.f;
        }
    }

    // ---- LDS transpose: value lands at output position j = r + 17*c ----
#pragma unroll
    for (int t = 0; t < 4; ++t) {
#pragma unroll
        for (int it = 0; it < 6; ++it) {
            const int r = it * 3 + g;
            if (active && r < DPATCH) {
                smem[(wslot * 4 + t) * NPATCH + r + DPATCH * c] = v[t][it];
            }
        }
    }

    // ---- per-patch partial sums, then 8 interleaved shuffle chains ----
    float s[4], q[4];
#pragma unroll
    for (int t = 0; t < 4; ++t) {
        s[t] = 0.f; q[t] = 0.f;
#pragma unroll
        for (int it = 0; it < 6; ++it) {
            s[t] += v[t][it];
            q[t] += v[t][it] * v[t][it];
        }
    }
#pragma unroll
    for (int off = 32; off > 0; off >>= 1) {
#pragma unroll
        for (int t = 0; t < 4; ++t) {
            s[t] += __shfl_xor(s[t], off, 64);
            q[t] += __shfl_xor(q[t], off, 64);
        }
    }

    // ---- normalize + coalesced nontemporal stores ----
#pragma unroll
    for (int t = 0; t < 4; ++t) {
        const float mean = s[t] * (1.0f / 289.0f);
        float var = (q[t] - 289.0f * mean * mean) * (1.0f / 288.0f);
        var = fmaxf(var, 0.0f);
        const float inv = 1.0f / (sqrtf(var) + 1e-4f);
#pragma unroll
        for (int k = 0; k < 5; ++k) {
            const int j = lane + (k << 6);
            if (j < NPATCH) {
                const float z = (smem[(wslot * 4 + t) * NPATCH + j] - mean) * inv;
                __builtin_nontemporal_store(z, &op[t][j]);
            }
        }
    }
}

extern "C" void kernel_launch(void* const* d_in, const int* in_sizes, int n_in,
                              void* d_out, int out_size, void* d_ws, size_t ws_size,
                              hipStream_t stream) {
    const float* img1  = (const float*)d_in[0];
    const float* img2  = (const float*)d_in[1];
    const int* matches = (const int*)d_in[2];
    float* out         = (float*)d_out;

    int* hist  = (int*)d_ws;                       // 1024 ints
    int* tasks = (int*)((char*)d_ws + 4096);       // 65536 ints

    hipLaunchKernelGGL(zero_hist_kernel, dim3(1), dim3(256), 0, stream, hist);
    hipLaunchKernelGGL(hist_kernel, dim3(NTASK / 256), dim3(256), 0, stream,
                       matches, hist);
    hipLaunchKernelGGL(scan_kernel, dim3(1), dim3(64), 0, stream, hist);
    hipLaunchKernelGGL(scatter_kernel, dim3(NTASK / 256), dim3(256), 0, stream,
                       matches, hist, tasks);

    // 65536 tasks / 4 per wave = 16384 waves = 4096 blocks of 256
    hipLaunchKernelGGL(extract_patch_kernel, dim3(4096), dim3(256), 0, stream,
                       img1, img2, matches, tasks, out);
}